// Round 5
// baseline (622.551 us; speedup 1.0000x reference)
//
#include <hip/hip_runtime.h>

#define NN 20000   // nodes
#define EE 640000  // edges
#define CAP 2048   // LDS edge-cache (int2) = 16 KB -> no occupancy throttle
#define WTP 200    // padded k-stride of transposed weight (breaks bank conflict)

typedef __attribute__((ext_vector_type(8))) short short8;
typedef __attribute__((ext_vector_type(4))) float float4v;
typedef __attribute__((ext_vector_type(2))) float float2v;
typedef __attribute__((ext_vector_type(4))) unsigned uint4v;

__device__ __forceinline__ unsigned bf16rn(float x) {
    unsigned u = __float_as_uint(x);
    return (u + 0x7FFFu + ((u >> 16) & 1u)) >> 16;
}
__device__ __forceinline__ unsigned pack2(float a, float b) {
    return bf16rn(a) | (bf16rn(b) << 16);
}
__device__ __forceinline__ float bflo(unsigned u) { return __uint_as_float(u << 16); }
__device__ __forceinline__ float bfhi(unsigned u) { return __uint_as_float(u & 0xFFFF0000u); }

__global__ void build_rowptr_k(const int* __restrict__ rows, int* __restrict__ rp) {
    int r = blockIdx.x * blockDim.x + threadIdx.x;
    if (r > NN) return;
    int lo = 0, hi = EE;
    while (lo < hi) {
        int mid = (lo + hi) >> 1;
        if (rows[mid] < r) lo = mid + 1; else hi = mid;
    }
    rp[r] = lo;
}

// inputs[b][n][f] fp32 -> xb[n][b*64+f] bf16 (node-major, matches y1/y2)
// one thread = 32B in -> 16B out (uint4 store), 10000 blocks
__global__ __launch_bounds__(256) void castxb_k(const float* __restrict__ inp,
                                                unsigned* __restrict__ xb) {
    int i = blockIdx.x * 256 + threadIdx.x;   // over NN*128 uint4 outputs
    int n = i >> 7, c = i & 127;              // c = b*8 + f8
    int b = c >> 3, f8 = c & 7;
    const float* p = inp + ((size_t)b * NN + n) * 64 + f8 * 8;
    float4 u0 = *(const float4*)(p);
    float4 u1 = *(const float4*)(p + 4);
    uint4 o;
    o.x = pack2(u0.x, u0.y); o.y = pack2(u0.z, u0.w);
    o.z = pack2(u1.x, u1.y); o.w = pack2(u1.z, u1.w);
    *(uint4*)(xb + (size_t)n * 512 + c * 4) = o;
}

// Wt[o][k'] bf16, k' = m*64+f, Chebyshev fold: m0: W0-W2, m1: W1, m2: 2*W2
__global__ void wtprep_k(const float* __restrict__ W, unsigned short* __restrict__ wt) {
    int i = blockIdx.x * 256 + threadIdx.x;
    if (i >= 64 * 192) return;
    int o = i / 192, kp = i - o * 192;
    int m = kp >> 6, f = kp & 63;
    float w = W[(f * 3 + m) * 64 + o];
    if (m == 0) w -= W[(f * 3 + 2) * 64 + o];
    else if (m == 2) w += w;
    wt[o * WTP + kp] = (unsigned short)bf16rn(w);
}

__device__ __forceinline__ void accum(const uint4v& q, int vbits,
                                      float2v& ac0, float2v& ac1,
                                      float2v& ac2, float2v& ac3) {
    float v_ = __int_as_float(vbits);
    float2v vv = {v_, v_};
    float2v p0 = {bflo(q[0]), bfhi(q[0])};
    float2v p1 = {bflo(q[1]), bfhi(q[1])};
    float2v p2 = {bflo(q[2]), bfhi(q[2])};
    float2v p3 = {bflo(q[3]), bfhi(q[3])};
    ac0 = __builtin_elementwise_fma(vv, p0, ac0);
    ac1 = __builtin_elementwise_fma(vv, p1, ac1);
    ac2 = __builtin_elementwise_fma(vv, p2, ac2);
    ac3 = __builtin_elementwise_fma(vv, p3, ac3);
}

// gather load, L1-streaming (nt): random cols give ~1% L1 hit; allocating
// the miss through L1 tags/MSHRs is the suspected throughput pipe.
__device__ __forceinline__ uint4v ldnt(const char* p) {
    return __builtin_nontemporal_load((const uint4v*)p);
}

// dst[n][c] = sum_e v * src[col][c], bf16 in/out.
// 1D grid of 10000 blocks, XCD-pinned slices: slice = (bid&7) + 8*((bid>>3)/625)
// so each XCD's 4MB L2 holds exactly one 2.56MB channel-slice at a time.
// Evidence (rounds 2-4): dur invariant to VALU count, unroll depth, and
// forced scheduling -> memory-path throughput ceiling, not latency. This
// round probes the L1 allocation path via nt loads. Loop is the proven
// minimal 4-deep structure (VGPR 28). NO goto/ping-pong CFG (round-1:
// scratch spills, WRITE 40->825 MB, 3.6x regression).
__global__ __launch_bounds__(256, 8) void spmm_bf16_k(
    const unsigned* __restrict__ src, const int* __restrict__ cols,
    const float* __restrict__ vals, const int* __restrict__ rp,
    unsigned* __restrict__ dst) {
    __shared__ int2 lcv[CAP];
    int bid = blockIdx.x;
    int xcd = bid & 7, j = bid >> 3;
    int chunk = j % 625;
    int s = xcd + ((j / 625) << 3);
    int t = threadIdx.x;
    int n0 = chunk * 32;
    int eBase = rp[n0];
    int eCap = min(rp[n0 + 32], eBase + CAP);
    for (int i = eBase + t; i < eCap; i += 256)
        lcv[i - eBase] = make_int2(cols[i], __float_as_int(vals[i]));
    __syncthreads();

    int node = n0 + (t >> 3);
    unsigned tOff = (unsigned)(s * 128 + (t & 7) * 16);   // byte offset within row
    const char* sb = (const char*)src;                    // uniform SGPR base
    int e0 = rp[node], e1 = rp[node + 1];
    int eL = min(e1, eCap);
    int le = e0 - eBase, lEnd = eL - eBase;
    float2v ac0 = {0,0}, ac1 = {0,0}, ac2 = {0,0}, ac3 = {0,0};

    int e = le;
    // 4-deep pipelined main loop: 4 independent gathers in flight per wave
    for (; e + 4 <= lEnd; e += 4) {
        int2 c0 = lcv[e],     c1 = lcv[e + 1];
        int2 c2 = lcv[e + 2], c3 = lcv[e + 3];
        uint4v q0 = ldnt(sb + (((unsigned)c0.x << 11) + tOff));
        uint4v q1 = ldnt(sb + (((unsigned)c1.x << 11) + tOff));
        uint4v q2 = ldnt(sb + (((unsigned)c2.x << 11) + tOff));
        uint4v q3 = ldnt(sb + (((unsigned)c3.x << 11) + tOff));
        accum(q0, c0.y, ac0, ac1, ac2, ac3);
        accum(q1, c1.y, ac0, ac1, ac2, ac3);
        accum(q2, c2.y, ac0, ac1, ac2, ac3);
        accum(q3, c3.y, ac0, ac1, ac2, ac3);
    }
    for (; e < lEnd; ++e) {
        int2 cv = lcv[e];
        uint4v q = ldnt(sb + (((unsigned)cv.x << 11) + tOff));
        accum(q, cv.y, ac0, ac1, ac2, ac3);
    }
    for (int a = lEnd + eBase; a < e1; ++a) {   // overflow fallback (statistically never)
        int c = cols[a];
        uint4v q = ldnt(sb + (((unsigned)c << 11) + tOff));
        accum(q, __float_as_int(vals[a]), ac0, ac1, ac2, ac3);
    }
    uint4 o;
    o.x = pack2(ac0[0], ac0[1]); o.y = pack2(ac1[0], ac1[1]);
    o.z = pack2(ac2[0], ac2[1]); o.w = pack2(ac3[0], ac3[1]);
    *(uint4*)((char*)dst + (size_t)node * 2048 + tOff) = o;
}

// fallback (no ws room for xb): gather fp32 inputs directly, emit bf16 y1
__global__ __launch_bounds__(256, 8) void spmm1_f32_k(
    const float* __restrict__ inputs, const int* __restrict__ cols,
    const float* __restrict__ vals, const int* __restrict__ rp,
    unsigned* __restrict__ y1) {
    __shared__ int2 lcv[CAP];
    int s = blockIdx.y, t = threadIdx.x;
    int n0 = blockIdx.x * 32;
    int eBase = rp[n0];
    int eCap = min(rp[n0 + 32], eBase + CAP);
    for (int i = eBase + t; i < eCap; i += 256)
        lcv[i - eBase] = make_int2(cols[i], __float_as_int(vals[i]));
    __syncthreads();

    int node = n0 + (t >> 3);
    const float* sp = inputs + (size_t)(s >> 1) * NN * 64 + (s & 1) * 32 + (t & 7) * 4;
    int e0 = rp[node], e1 = rp[node + 1];
    int eL = min(e1, eCap);
    float4 acc = make_float4(0.f, 0.f, 0.f, 0.f);
    #pragma unroll 2
    for (int e = e0; e < eL; ++e) {
        int2 cv = lcv[e - eBase];
        float v = __int_as_float(cv.y);
        float4 xv = *(const float4*)(sp + (size_t)cv.x * 64);
        acc.x += v * xv.x; acc.y += v * xv.y; acc.z += v * xv.z; acc.w += v * xv.w;
    }
    for (int e = eL; e < e1; ++e) {
        int c = cols[e]; float v = vals[e];
        float4 xv = *(const float4*)(sp + (size_t)c * 64);
        acc.x += v * xv.x; acc.y += v * xv.y; acc.z += v * xv.z; acc.w += v * xv.w;
    }
    uint2 o; o.x = pack2(acc.x, acc.y); o.y = pack2(acc.z, acc.w);
    *(uint2*)(y1 + (size_t)node * 512 + (s >> 1) * 32 + (s & 1) * 16 + (t & 7) * 2) = o;
}

// MFMA GEMM: out[b*NN+n][o] = [x0|y1|y2](bf16) @ Wt + bias, fp32 out.
// block = 64 nodes x 64 out x 2 b-iters; 4 waves, each 16n x 64o, K=192.
__global__ __launch_bounds__(256) void gemm_k(
    const float* __restrict__ inputs, const unsigned* __restrict__ xb,
    const unsigned* __restrict__ y1, const unsigned* __restrict__ y2,
    const unsigned short* __restrict__ wt, const float* __restrict__ bias,
    float* __restrict__ out) {
    __shared__ unsigned short wl[64 * WTP];   // 25.6 KB
    int t = threadIdx.x;
    for (int i = t; i < 1600; i += 256)
        ((uint4*)wl)[i] = ((const uint4*)wt)[i];
    __syncthreads();

    int w = t >> 6, l = t & 63;
    int lr = l & 15, lq = l >> 4;
    int n0 = blockIdx.x * 64 + w * 16;
    int nA = min(n0 + lr, NN - 1);   // clamped A-row (tail block)
    float bv0 = bias[lr], bv1 = bias[16 + lr], bv2 = bias[32 + lr], bv3 = bias[48 + lr];

    #pragma unroll
    for (int bb = 0; bb < 2; ++bb) {
        int b = blockIdx.y * 2 + bb;
        const unsigned* p1 = y1 + (size_t)nA * 512 + b * 32 + lq * 4;
        const unsigned* p2 = y2 + (size_t)nA * 512 + b * 32 + lq * 4;

        short8 a[6];
        if (xb) {
            const unsigned* p0 = xb + (size_t)nA * 512 + b * 32 + lq * 4;
            a[0] = *(const short8*)(p0);
            a[1] = *(const short8*)(p0 + 16);
        } else {
            const float* px = inputs + ((size_t)b * NN + nA) * 64 + lq * 8;
            float4 u0 = *(const float4*)(px);
            float4 u1 = *(const float4*)(px + 4);
            float4 u2 = *(const float4*)(px + 32);
            float4 u3 = *(const float4*)(px + 36);
            short8 t0, t1;
            t0[0] = (short)bf16rn(u0.x); t0[1] = (short)bf16rn(u0.y);
            t0[2] = (short)bf16rn(u0.z); t0[3] = (short)bf16rn(u0.w);
            t0[4] = (short)bf16rn(u1.x); t0[5] = (short)bf16rn(u1.y);
            t0[6] = (short)bf16rn(u1.z); t0[7] = (short)bf16rn(u1.w);
            t1[0] = (short)bf16rn(u2.x); t1[1] = (short)bf16rn(u2.y);
            t1[2] = (short)bf16rn(u2.z); t1[3] = (short)bf16rn(u2.w);
            t1[4] = (short)bf16rn(u3.x); t1[5] = (short)bf16rn(u3.y);
            t1[6] = (short)bf16rn(u3.z); t1[7] = (short)bf16rn(u3.w);
            a[0] = t0; a[1] = t1;
        }
        a[2] = *(const short8*)(p1);
        a[3] = *(const short8*)(p1 + 16);
        a[4] = *(const short8*)(p2);
        a[5] = *(const short8*)(p2 + 16);

        float4v acc0 = {0,0,0,0}, acc1 = {0,0,0,0}, acc2 = {0,0,0,0}, acc3 = {0,0,0,0};
        #pragma unroll
        for (int ks = 0; ks < 6; ++ks) {
            int kk = ks * 32 + lq * 8;
            short8 b0 = *(const short8*)&wl[(lr +  0) * WTP + kk];
            short8 b1 = *(const short8*)&wl[(lr + 16) * WTP + kk];
            short8 b2 = *(const short8*)&wl[(lr + 32) * WTP + kk];
            short8 b3 = *(const short8*)&wl[(lr + 48) * WTP + kk];
            acc0 = __builtin_amdgcn_mfma_f32_16x16x32_bf16(a[ks], b0, acc0, 0, 0, 0);
            acc1 = __builtin_amdgcn_mfma_f32_16x16x32_bf16(a[ks], b1, acc1, 0, 0, 0);
            acc2 = __builtin_amdgcn_mfma_f32_16x16x32_bf16(a[ks], b2, acc2, 0, 0, 0);
            acc3 = __builtin_amdgcn_mfma_f32_16x16x32_bf16(a[ks], b3, acc3, 0, 0, 0);
        }
        #pragma unroll
        for (int r = 0; r < 4; ++r) {
            int n = n0 + lq * 4 + r;
            if (n < NN) {
                float* po = out + ((size_t)b * NN + n) * 64;
                po[lr]      = acc0[r] + bv0;
                po[16 + lr] = acc1[r] + bv1;
                po[32 + lr] = acc2[r] + bv2;
                po[48 + lr] = acc3[r] + bv3;
            }
        }
    }
}

extern "C" void kernel_launch(void* const* d_in, const int* in_sizes, int n_in,
                              void* d_out, int out_size, void* d_ws, size_t ws_size,
                              hipStream_t stream) {
    const float* inputs  = (const float*)d_in[0];
    const int*   sp_rows = (const int*)d_in[1];
    const int*   sp_cols = (const int*)d_in[2];
    const float* sp_vals = (const float*)d_in[3];
    const float* weight  = (const float*)d_in[4];
    const float* biases  = (const float*)d_in[5];
    float* out = (float*)d_out;

    const size_t ybytes = (size_t)NN * 512 * 4;   // 40.96 MB per bf16 matrix
    char* base = (char*)d_ws;
    unsigned* y1 = (unsigned*)base;
    unsigned* y2 = (unsigned*)(base + ybytes);
    size_t off = 2 * ybytes;
    const size_t tail = (((size_t)(NN + 1) * 4 + 15) & ~(size_t)15) + 64 * WTP * 2 + 64;
    bool useXb = ws_size >= 3 * ybytes + tail;
    unsigned* xb = nullptr;
    if (useXb) { xb = (unsigned*)(base + off); off += ybytes; }
    int* rp = (int*)(base + off);
    off += ((size_t)(NN + 1) * 4 + 15) & ~(size_t)15;
    unsigned short* wt = (unsigned short*)(base + off);

    build_rowptr_k<<<79, 256, 0, stream>>>(sp_rows, rp);
    wtprep_k<<<48, 256, 0, stream>>>(weight, wt);
    if (useXb) {
        castxb_k<<<10000, 256, 0, stream>>>(inputs, xb);
        spmm_bf16_k<<<10000, 256, 0, stream>>>(xb, sp_cols, sp_vals, rp, y1);
    } else {
        spmm1_f32_k<<<dim3(625, 32), 256, 0, stream>>>(inputs, sp_cols, sp_vals, rp, y1);
    }
    spmm_bf16_k<<<10000, 256, 0, stream>>>(y1, sp_cols, sp_vals, rp, y2);
    gemm_k<<<dim3(313, 8), 256, 0, stream>>>(inputs, xb, y1, y2, wt, biases, out);
}

// Round 6
// 346.016 us; speedup vs baseline: 1.7992x; 1.7992x over previous
//
#include <hip/hip_runtime.h>

#define NN 20000   // nodes
#define EE 640000  // edges
#define CAP 2048   // LDS edge-cache (int2) = 16 KB -> no occupancy throttle
#define WTP 200    // padded k-stride of transposed weight (breaks bank conflict)

typedef __attribute__((ext_vector_type(8))) short short8;
typedef __attribute__((ext_vector_type(4))) float float4v;
typedef __attribute__((ext_vector_type(2))) float float2v;

__device__ __forceinline__ unsigned bf16rn(float x) {
    unsigned u = __float_as_uint(x);
    return (u + 0x7FFFu + ((u >> 16) & 1u)) >> 16;
}
__device__ __forceinline__ unsigned pack2(float a, float b) {
    return bf16rn(a) | (bf16rn(b) << 16);
}
__device__ __forceinline__ float bflo(unsigned u) { return __uint_as_float(u << 16); }
__device__ __forceinline__ float bfhi(unsigned u) { return __uint_as_float(u & 0xFFFF0000u); }

// Fused prep: blocks [0,nCast) cast inputs->xb; [nCast,nCast+79) rowptr;
// [nCast+79, nCast+127) weight fold. All independent -> overlap + 2 fewer
// launches. nCast = 10000 (or 0 on the no-xb fallback path).
__global__ __launch_bounds__(256) void prep_k(
    const float* __restrict__ inp, unsigned* __restrict__ xb,
    const int* __restrict__ rows, int* __restrict__ rp,
    const float* __restrict__ W, unsigned short* __restrict__ wt,
    int nCast) {
    int bid = blockIdx.x, t = threadIdx.x;
    if (bid < nCast) {
        // inputs[b][n][f] fp32 -> xb[n][b*64+f] bf16; 32B in -> 16B out
        int i = bid * 256 + t;                    // over NN*128 uint4 outputs
        int n = i >> 7, c = i & 127;              // c = b*8 + f8
        int b = c >> 3, f8 = c & 7;
        const float* p = inp + ((size_t)b * NN + n) * 64 + f8 * 8;
        float4 u0 = *(const float4*)(p);
        float4 u1 = *(const float4*)(p + 4);
        uint4 o;
        o.x = pack2(u0.x, u0.y); o.y = pack2(u0.z, u0.w);
        o.z = pack2(u1.x, u1.y); o.w = pack2(u1.z, u1.w);
        *(uint4*)(xb + (size_t)n * 512 + c * 4) = o;
    } else if (bid < nCast + 79) {
        int r = (bid - nCast) * 256 + t;
        if (r > NN) return;
        int lo = 0, hi = EE;
        while (lo < hi) {
            int mid = (lo + hi) >> 1;
            if (rows[mid] < r) lo = mid + 1; else hi = mid;
        }
        rp[r] = lo;
    } else {
        // Wt[o][k'] bf16, k' = m*64+f; Chebyshev fold: m0: W0-W2, m2: 2*W2
        int i = (bid - nCast - 79) * 256 + t;
        if (i >= 64 * 192) return;
        int o = i / 192, kp = i - o * 192;
        int m = kp >> 6, f = kp & 63;
        float w = W[(f * 3 + m) * 64 + o];
        if (m == 0) w -= W[(f * 3 + 2) * 64 + o];
        else if (m == 2) w += w;
        wt[o * WTP + kp] = (unsigned short)bf16rn(w);
    }
}

__device__ __forceinline__ void accum(const uint4& q, int vbits,
                                      float2v& ac0, float2v& ac1,
                                      float2v& ac2, float2v& ac3) {
    float v_ = __int_as_float(vbits);
    float2v vv = {v_, v_};
    float2v p0 = {bflo(q.x), bfhi(q.x)};
    float2v p1 = {bflo(q.y), bfhi(q.y)};
    float2v p2 = {bflo(q.z), bfhi(q.z)};
    float2v p3 = {bflo(q.w), bfhi(q.w)};
    ac0 = __builtin_elementwise_fma(vv, p0, ac0);
    ac1 = __builtin_elementwise_fma(vv, p1, ac1);
    ac2 = __builtin_elementwise_fma(vv, p2, ac2);
    ac3 = __builtin_elementwise_fma(vv, p3, ac3);
}

// dst[n][c] = sum_e v * src[col][c], bf16 in/out.
// 1D grid of 10000 blocks, XCD-pinned slices: slice = (bid&7) + 8*((bid>>3)/625)
// so each XCD's 4MB L2 holds exactly one 2.56MB channel-slice at a time.
// ROOFLINE NOTE (rounds 2-5): dur invariant to VALU count (r2), unroll depth
// (r3), forced scheduling (r4); nt loads break L2 allocation (r5: FETCH
// 66->408MB, 2.4x slower). Achieved 15.6 TB/s aggregate L2 service = ~79%
// of per-XCD channel peak on random 64B sectors -> this loop is at the L2
// random-access ceiling. Do not touch. NO goto/ping-pong CFG (r1: spills).
__global__ __launch_bounds__(256, 8) void spmm_bf16_k(
    const unsigned* __restrict__ src, const int* __restrict__ cols,
    const float* __restrict__ vals, const int* __restrict__ rp,
    unsigned* __restrict__ dst) {
    __shared__ int2 lcv[CAP];
    int bid = blockIdx.x;
    int xcd = bid & 7, j = bid >> 3;
    int chunk = j % 625;
    int s = xcd + ((j / 625) << 3);
    int t = threadIdx.x;
    int n0 = chunk * 32;
    int eBase = rp[n0];
    int eCap = min(rp[n0 + 32], eBase + CAP);
    for (int i = eBase + t; i < eCap; i += 256)
        lcv[i - eBase] = make_int2(cols[i], __float_as_int(vals[i]));
    __syncthreads();

    int node = n0 + (t >> 3);
    unsigned tOff = (unsigned)(s * 128 + (t & 7) * 16);   // byte offset within row
    const char* sb = (const char*)src;                    // uniform SGPR base
    int e0 = rp[node], e1 = rp[node + 1];
    int eL = min(e1, eCap);
    int le = e0 - eBase, lEnd = eL - eBase;
    float2v ac0 = {0,0}, ac1 = {0,0}, ac2 = {0,0}, ac3 = {0,0};

    int e = le;
    // 4-deep pipelined main loop: 4 independent gathers in flight per wave
    for (; e + 4 <= lEnd; e += 4) {
        int2 c0 = lcv[e],     c1 = lcv[e + 1];
        int2 c2 = lcv[e + 2], c3 = lcv[e + 3];
        uint4 q0 = *(const uint4*)(sb + (((unsigned)c0.x << 11) + tOff));
        uint4 q1 = *(const uint4*)(sb + (((unsigned)c1.x << 11) + tOff));
        uint4 q2 = *(const uint4*)(sb + (((unsigned)c2.x << 11) + tOff));
        uint4 q3 = *(const uint4*)(sb + (((unsigned)c3.x << 11) + tOff));
        accum(q0, c0.y, ac0, ac1, ac2, ac3);
        accum(q1, c1.y, ac0, ac1, ac2, ac3);
        accum(q2, c2.y, ac0, ac1, ac2, ac3);
        accum(q3, c3.y, ac0, ac1, ac2, ac3);
    }
    for (; e < lEnd; ++e) {
        int2 cv = lcv[e];
        uint4 q = *(const uint4*)(sb + (((unsigned)cv.x << 11) + tOff));
        accum(q, cv.y, ac0, ac1, ac2, ac3);
    }
    for (int a = lEnd + eBase; a < e1; ++a) {   // overflow fallback (statistically never)
        int c = cols[a];
        uint4 q = *(const uint4*)(sb + (((unsigned)c << 11) + tOff));
        accum(q, __float_as_int(vals[a]), ac0, ac1, ac2, ac3);
    }
    uint4 o;
    o.x = pack2(ac0[0], ac0[1]); o.y = pack2(ac1[0], ac1[1]);
    o.z = pack2(ac2[0], ac2[1]); o.w = pack2(ac3[0], ac3[1]);
    *(uint4*)((char*)dst + (size_t)node * 2048 + tOff) = o;
}

// fallback (no ws room for xb): gather fp32 inputs directly, emit bf16 y1
__global__ __launch_bounds__(256, 8) void spmm1_f32_k(
    const float* __restrict__ inputs, const int* __restrict__ cols,
    const float* __restrict__ vals, const int* __restrict__ rp,
    unsigned* __restrict__ y1) {
    __shared__ int2 lcv[CAP];
    int s = blockIdx.y, t = threadIdx.x;
    int n0 = blockIdx.x * 32;
    int eBase = rp[n0];
    int eCap = min(rp[n0 + 32], eBase + CAP);
    for (int i = eBase + t; i < eCap; i += 256)
        lcv[i - eBase] = make_int2(cols[i], __float_as_int(vals[i]));
    __syncthreads();

    int node = n0 + (t >> 3);
    const float* sp = inputs + (size_t)(s >> 1) * NN * 64 + (s & 1) * 32 + (t & 7) * 4;
    int e0 = rp[node], e1 = rp[node + 1];
    int eL = min(e1, eCap);
    float4 acc = make_float4(0.f, 0.f, 0.f, 0.f);
    #pragma unroll 2
    for (int e = e0; e < eL; ++e) {
        int2 cv = lcv[e - eBase];
        float v = __int_as_float(cv.y);
        float4 xv = *(const float4*)(sp + (size_t)cv.x * 64);
        acc.x += v * xv.x; acc.y += v * xv.y; acc.z += v * xv.z; acc.w += v * xv.w;
    }
    for (int e = eL; e < e1; ++e) {
        int c = cols[e]; float v = vals[e];
        float4 xv = *(const float4*)(sp + (size_t)c * 64);
        acc.x += v * xv.x; acc.y += v * xv.y; acc.z += v * xv.z; acc.w += v * xv.w;
    }
    uint2 o; o.x = pack2(acc.x, acc.y); o.y = pack2(acc.z, acc.w);
    *(uint2*)(y1 + (size_t)node * 512 + (s >> 1) * 32 + (s & 1) * 16 + (t & 7) * 2) = o;
}

// MFMA GEMM: out[b*NN+n][o] = [x0|y1|y2](bf16) @ Wt + bias, fp32 out.
// block = 64 nodes x 64 out x 4 b-iters; 4 waves, each 16n x 64o, K=192.
// 4 batches/block amortizes the 25.6KB LDS weight fill + barrier over 2x
// the work vs the previous 2-batch version.
__global__ __launch_bounds__(256) void gemm_k(
    const float* __restrict__ inputs, const unsigned* __restrict__ xb,
    const unsigned* __restrict__ y1, const unsigned* __restrict__ y2,
    const unsigned short* __restrict__ wt, const float* __restrict__ bias,
    float* __restrict__ out) {
    __shared__ unsigned short wl[64 * WTP];   // 25.6 KB
    int t = threadIdx.x;
    for (int i = t; i < 1600; i += 256)
        ((uint4*)wl)[i] = ((const uint4*)wt)[i];
    __syncthreads();

    int w = t >> 6, l = t & 63;
    int lr = l & 15, lq = l >> 4;
    int n0 = blockIdx.x * 64 + w * 16;
    int nA = min(n0 + lr, NN - 1);   // clamped A-row (tail block)
    float bv0 = bias[lr], bv1 = bias[16 + lr], bv2 = bias[32 + lr], bv3 = bias[48 + lr];

    #pragma unroll 2
    for (int bb = 0; bb < 4; ++bb) {
        int b = blockIdx.y * 4 + bb;
        const unsigned* p1 = y1 + (size_t)nA * 512 + b * 32 + lq * 4;
        const unsigned* p2 = y2 + (size_t)nA * 512 + b * 32 + lq * 4;

        short8 a[6];
        if (xb) {
            const unsigned* p0 = xb + (size_t)nA * 512 + b * 32 + lq * 4;
            a[0] = *(const short8*)(p0);
            a[1] = *(const short8*)(p0 + 16);
        } else {
            const float* px = inputs + ((size_t)b * NN + nA) * 64 + lq * 8;
            float4 u0 = *(const float4*)(px);
            float4 u1 = *(const float4*)(px + 4);
            float4 u2 = *(const float4*)(px + 32);
            float4 u3 = *(const float4*)(px + 36);
            short8 t0, t1;
            t0[0] = (short)bf16rn(u0.x); t0[1] = (short)bf16rn(u0.y);
            t0[2] = (short)bf16rn(u0.z); t0[3] = (short)bf16rn(u0.w);
            t0[4] = (short)bf16rn(u1.x); t0[5] = (short)bf16rn(u1.y);
            t0[6] = (short)bf16rn(u1.z); t0[7] = (short)bf16rn(u1.w);
            t1[0] = (short)bf16rn(u2.x); t1[1] = (short)bf16rn(u2.y);
            t1[2] = (short)bf16rn(u2.z); t1[3] = (short)bf16rn(u2.w);
            t1[4] = (short)bf16rn(u3.x); t1[5] = (short)bf16rn(u3.y);
            t1[6] = (short)bf16rn(u3.z); t1[7] = (short)bf16rn(u3.w);
            a[0] = t0; a[1] = t1;
        }
        a[2] = *(const short8*)(p1);
        a[3] = *(const short8*)(p1 + 16);
        a[4] = *(const short8*)(p2);
        a[5] = *(const short8*)(p2 + 16);

        float4v acc0 = {0,0,0,0}, acc1 = {0,0,0,0}, acc2 = {0,0,0,0}, acc3 = {0,0,0,0};
        #pragma unroll
        for (int ks = 0; ks < 6; ++ks) {
            int kk = ks * 32 + lq * 8;
            short8 b0 = *(const short8*)&wl[(lr +  0) * WTP + kk];
            short8 b1 = *(const short8*)&wl[(lr + 16) * WTP + kk];
            short8 b2 = *(const short8*)&wl[(lr + 32) * WTP + kk];
            short8 b3 = *(const short8*)&wl[(lr + 48) * WTP + kk];
            acc0 = __builtin_amdgcn_mfma_f32_16x16x32_bf16(a[ks], b0, acc0, 0, 0, 0);
            acc1 = __builtin_amdgcn_mfma_f32_16x16x32_bf16(a[ks], b1, acc1, 0, 0, 0);
            acc2 = __builtin_amdgcn_mfma_f32_16x16x32_bf16(a[ks], b2, acc2, 0, 0, 0);
            acc3 = __builtin_amdgcn_mfma_f32_16x16x32_bf16(a[ks], b3, acc3, 0, 0, 0);
        }
        #pragma unroll
        for (int r = 0; r < 4; ++r) {
            int n = n0 + lq * 4 + r;
            if (n < NN) {
                float* po = out + ((size_t)b * NN + n) * 64;
                po[lr]      = acc0[r] + bv0;
                po[16 + lr] = acc1[r] + bv1;
                po[32 + lr] = acc2[r] + bv2;
                po[48 + lr] = acc3[r] + bv3;
            }
        }
    }
}

extern "C" void kernel_launch(void* const* d_in, const int* in_sizes, int n_in,
                              void* d_out, int out_size, void* d_ws, size_t ws_size,
                              hipStream_t stream) {
    const float* inputs  = (const float*)d_in[0];
    const int*   sp_rows = (const int*)d_in[1];
    const int*   sp_cols = (const int*)d_in[2];
    const float* sp_vals = (const float*)d_in[3];
    const float* weight  = (const float*)d_in[4];
    const float* biases  = (const float*)d_in[5];
    float* out = (float*)d_out;

    const size_t ybytes = (size_t)NN * 512 * 4;   // 40.96 MB per bf16 matrix
    char* base = (char*)d_ws;
    unsigned* y1 = (unsigned*)base;
    unsigned* y2 = (unsigned*)(base + ybytes);
    size_t off = 2 * ybytes;
    const size_t tail = (((size_t)(NN + 1) * 4 + 15) & ~(size_t)15) + 64 * WTP * 2 + 64;
    bool useXb = ws_size >= 3 * ybytes + tail;
    unsigned* xb = nullptr;
    if (useXb) { xb = (unsigned*)(base + off); off += ybytes; }
    int* rp = (int*)(base + off);
    off += ((size_t)(NN + 1) * 4 + 15) & ~(size_t)15;
    unsigned short* wt = (unsigned short*)(base + off);

    if (useXb) {
        prep_k<<<10127, 256, 0, stream>>>(inputs, xb, sp_rows, rp, weight, wt, 10000);
        spmm_bf16_k<<<10000, 256, 0, stream>>>(xb, sp_cols, sp_vals, rp, y1);
    } else {
        prep_k<<<127, 256, 0, stream>>>(inputs, nullptr, sp_rows, rp, weight, wt, 0);
        spmm1_f32_k<<<dim3(625, 32), 256, 0, stream>>>(inputs, sp_cols, sp_vals, rp, y1);
    }
    spmm_bf16_k<<<10000, 256, 0, stream>>>(y1, sp_cols, sp_vals, rp, y2);
    gemm_k<<<dim3(313, 4), 256, 0, stream>>>(inputs, xb, y1, y2, wt, biases, out);
}